// Round 18
// baseline (80.239 us; speedup 1.0000x reference)
//
#include <hip/hip_runtime.h>
#include <cstddef>

using u16 = unsigned short;
typedef __attribute__((ext_vector_type(8))) short bf16x8;
typedef __attribute__((ext_vector_type(4))) short bf16x4;
typedef __attribute__((ext_vector_type(4))) float f32x4;

constexpr int kB = 4, kL = 256, kR = 64, kH = 768, kTE = 100;
constexpr size_t HH = (size_t)kH * kH;

// ---- output offsets (floats) in return order ----
constexpr size_t OFF_FSS = 0;
constexpr size_t OFF_FSE = OFF_FSS + kB * kL;
constexpr size_t OFF_FOS = OFF_FSE + kB * kL;
constexpr size_t OFF_FOE = OFF_FOS + (size_t)kB * kL * kR;
constexpr size_t OFF_BOS = OFF_FOE + (size_t)kB * kL * kR;
constexpr size_t OFF_BOE = OFF_BOS + kB * kL;
constexpr size_t OFF_BSS = OFF_BOE + kB * kL;
constexpr size_t OFF_BSE = OFF_BSS + (size_t)kB * kL * kR;

// ---- workspace layout (float units), no aliasing ----
constexpr size_t WS_WTALL   = 0;                                   // 10xHH u16 (2..7 used)
constexpr size_t WS_EMBSB   = WS_WTALL   + 10 * HH / 2;            // 1024x768 u16
constexpr size_t WS_RELEMBB = WS_EMBSB   + (1024 * 768) / 2;       // 64x768 u16
constexpr size_t WS_HGSB    = WS_RELEMBB + (64 * 768) / 2;         // 4x768 u16
constexpr size_t WS_BRELB   = WS_HGSB    + (4 * 768) / 2;          // 64x768 u16
constexpr size_t WS_TOKPB   = WS_BRELB   + (64 * 768) / 2;         // 2x1024x768 u16
constexpr size_t WS_RELPF   = WS_TOKPB   + (2 * 1024 * 768) / 2;   // 64x768 f32
constexpr size_t WS_RELPB   = WS_RELPF   + 64 * 768;
constexpr size_t WS_HGPF    = WS_RELPB   + 64 * 768;               // 4x768 f32
constexpr size_t WS_HGPB    = WS_HGPF    + 4 * 768;
constexpr size_t WS_DD      = WS_HGPB    + 4 * 768;                // 4x1024 f32 (fc dots)
constexpr size_t WS_DA      = WS_DD      + 4 * 1024;               // 4x1024 f32 (uA dots)
constexpr size_t WS_DB      = WS_DA      + 4 * 1024;               // 4x1024 f32 (uB dots)
constexpr size_t WS_UA      = WS_DB      + 4 * 1024;               // 4x768 f32
constexpr size_t WS_UB      = WS_UA      + 4 * 768;                // 4x768 f32
constexpr size_t WS_CC      = WS_UB      + 4 * 768;                // 8 f32
constexpr size_t WS_C4      = WS_CC      + 8;                      // 256 each
constexpr size_t WS_C5      = WS_C4 + 256;
constexpr size_t WS_C6      = WS_C5 + 256;
constexpr size_t WS_C7      = WS_C6 + 256;
constexpr size_t WS_T4      = WS_C7 + 256;                         // 1024 each
constexpr size_t WS_T5      = WS_T4 + 1024;
constexpr size_t WS_T6      = WS_T5 + 1024;
constexpr size_t WS_T7      = WS_T6 + 1024;

__device__ inline float fast_rcp(float x) {
#if __has_builtin(__builtin_amdgcn_rcpf)
    return __builtin_amdgcn_rcpf(x);
#else
    return 1.f / x;
#endif
}
__device__ inline float fast_exp2(float x) {
#if __has_builtin(__builtin_amdgcn_exp2f)
    return __builtin_amdgcn_exp2f(x);
#else
    return __exp2f(x);
#endif
}
__device__ inline u16 f2bf(float x) {   // RNE
    union { float f; unsigned u; } v; v.f = x;
    unsigned r = v.u + 0x7FFFu + ((v.u >> 16) & 1u);
    return (u16)(r >> 16);
}
__device__ inline float bf2f(u16 x) {
    union { unsigned u; float f; } v; v.u = ((unsigned)x) << 16;
    return v.f;
}
// VALU-only tanh: clamped Pade(7,6), reciprocal via magic init + 2 Newton steps.
// No transcendental-pipe ops. |err| < 5e-4 on all of R.
__device__ inline float tanh_valu(float x) {
    float xc = fminf(fmaxf(x, -4.97f), 4.97f);
    float t = xc * xc;
    float np = fmaf(t, fmaf(t, (t + 378.f), 17325.f), 135135.f);
    float dp = fmaf(t, fmaf(t, fmaf(t, 28.f, 3150.f), 62370.f), 135135.f);
    union { float f; unsigned u; } uu; uu.f = dp;
    uu.u = 0x7EF127EAu - uu.u;            // ~6% recip estimate (dp in [1.3e5, 4.1e6])
    float r = uu.f;
    r = r * fmaf(-dp, r, 2.f);
    r = r * fmaf(-dp, r, 2.f);
    return xc * np * r;
}

// ---- 1. mega-prep ----
__global__ __launch_bounds__(256) void k_prep_all(
        const float* __restrict__ embs, const float* __restrict__ rel_embs,
        const float* __restrict__ h_gs, const float* __restrict__ rel_transe,
        const float* __restrict__ fc_w, const float* __restrict__ fc_b,
        const float* __restrict__ Wm, const float* __restrict__ Wb,
        const float* __restrict__ rproj_w, const float* __restrict__ rproj_b,
        float* __restrict__ out, u16* __restrict__ embsB,
        u16* __restrict__ relembB, u16* __restrict__ hgsB, u16* __restrict__ brelB,
        u16* __restrict__ WtAll,
        float* __restrict__ uA, float* __restrict__ uB, float* __restrict__ cc,
        float* __restrict__ dd)
{
    __shared__ float sh[64 * 65];
    int bx = blockIdx.x, t = threadIdx.x;
    if (bx < 1024) {
        int tok = bx;
        const float* e = embs + (size_t)tok * kH;
        float s[8] = {0, 0, 0, 0, 0, 0, 0, 0};
        for (int h = t; h < kH; h += 256) {
            float x = e[h];
            embsB[(size_t)tok * kH + h] = f2bf(x);
#pragma unroll
            for (int j = 0; j < 8; j++) s[j] += x * fc_w[j * kH + h];
        }
#pragma unroll
        for (int off = 32; off; off >>= 1)
#pragma unroll
            for (int j = 0; j < 8; j++) s[j] += __shfl_down(s[j], off, 64);
        float(*red)[4] = (float(*)[4])sh;
        int wid = t >> 6;
        if ((t & 63) == 0) {
#pragma unroll
            for (int j = 0; j < 8; j++) red[j][wid] = s[j];
        }
        __syncthreads();
        if (t == 0) {
            float r[8];
#pragma unroll
            for (int j = 0; j < 8; j++) r[j] = red[j][0] + red[j][1] + red[j][2] + red[j][3];
            out[OFF_FSS + tok] = r[0] + fc_b[0];
            out[OFF_FSE + tok] = r[1] + fc_b[1];
            out[OFF_BOS + tok] = r[2] + fc_b[2];
            out[OFF_BOE + tok] = r[3] + fc_b[3];
            dd[0 * 1024 + tok] = r[4];
            dd[1 * 1024 + tok] = r[5];
            dd[2 * 1024 + tok] = r[6];
            dd[3 * 1024 + tok] = r[7];
        }
    } else if (bx < 1888) {
        int px = bx - 1024;
        int mi = 2 + px / 144, tile = px % 144;
        int kt = (tile / 12) * 64, nt = (tile % 12) * 64;
        const float* src = Wm + (size_t)mi * HH;
        u16* dst = WtAll + (size_t)mi * HH;
        float(*tl)[65] = (float(*)[65])sh;
        int r = t >> 2, cq = (t & 3) * 16;
        int row = kt + r;
#pragma unroll
        for (int q = 0; q < 4; q++) {
            float4 v = *(const float4*)(src + (size_t)row * kH + nt + cq + q * 4);
            tl[r][cq + q * 4 + 0] = v.x;
            tl[r][cq + q * 4 + 1] = v.y;
            tl[r][cq + q * 4 + 2] = v.z;
            tl[r][cq + q * 4 + 3] = v.w;
        }
        __syncthreads();
        u16* drow = dst + (size_t)(nt + r) * kH + kt + cq;
#pragma unroll
        for (int j = 0; j < 16; j++) drow[j] = f2bf(tl[cq + j][r]);
    } else if (bx < 2656) {
        int gx = bx - 1888;
        int p = gx / 192;
        int wid = t >> 6, lane = t & 63;
        int row = (gx % 192) * 4 + wid;
        const int wmI[4] = {0, 1, 8, 9};
        const float* W  = Wm + (size_t)wmI[p] * HH + (size_t)row * kH;
        const float* wa = fc_w + (size_t)((p & 1) ? 6 : 4) * kH;
        const float* wb = wa + kH;
        float sa = 0.f, sb = 0.f;
        for (int c = lane; c < kH; c += 64) {
            float wv = W[c];
            sa += wv * wa[c];
            sb += wv * wb[c];
        }
#pragma unroll
        for (int off = 32; off; off >>= 1) {
            sa += __shfl_xor(sa, off, 64);
            sb += __shfl_xor(sb, off, 64);
        }
        if (lane == 0) {
            if (p < 2) {
                uA[(2 * p) * kH + row]     = sa;
                uA[(2 * p + 1) * kH + row] = sb;
            } else {
                int q = p - 2;
                uB[(2 * q) * kH + row]     = sa + wa[row];
                uB[(2 * q + 1) * kH + row] = sb + wb[row];
            }
        }
    } else if (bx < 2720) {
        int r = bx - 2656;
        for (int h = t; h < kH; h += 256) relembB[r * kH + h] = f2bf(rel_embs[r * kH + h]);
    } else if (bx < 2724) {
        int r = bx - 2720;
        for (int h = t; h < kH; h += 256) hgsB[r * kH + h] = f2bf(h_gs[r * kH + h]);
    } else if (bx < 2788) {
        int r = bx - 2724;
        if (t < kTE) sh[t] = rel_transe[r * kTE + t];
        __syncthreads();
        float a0 = rproj_b[t], a1 = rproj_b[t + 256], a2 = rproj_b[t + 512];
        for (int k = 0; k < kTE; k++) {
            float rv = sh[k];
            const float* wr = rproj_w + (size_t)k * kH;
            a0 = fmaf(rv, wr[t], a0);
            a1 = fmaf(rv, wr[t + 256], a1);
            a2 = fmaf(rv, wr[t + 512], a2);
        }
        brelB[r * kH + t]       = f2bf(a0);
        brelB[r * kH + t + 256] = f2bf(a1);
        brelB[r * kH + t + 512] = f2bf(a2);
    } else {
        int j = bx - 2788;
        const int wbI[8] = {0, 0, 1, 1, 8, 8, 9, 9};
        const int fcI[8] = {4, 5, 6, 7, 4, 5, 6, 7};
        const float* wb = Wb + (size_t)wbI[j] * kH;
        const float* w  = fc_w + (size_t)fcI[j] * kH;
        float s = 0.f;
        for (int h = t; h < kH; h += 256) s += wb[h] * w[h];
#pragma unroll
        for (int off = 32; off; off >>= 1) s += __shfl_down(s, off, 64);
        int wid = t >> 6;
        if ((t & 63) == 0) sh[wid] = s;
        __syncthreads();
        if (t == 0) cc[j] = sh[0] + sh[1] + sh[2] + sh[3];
    }
}

// ---- 2. per-token uA/uB dots (coalesced) + batched MFMA GEMM ----
struct GemmJob {
    const u16* A; const u16* Wt; const float* bias;
    float* C; u16* Cbf; const float* rowmask;
    int M; int K; int ldc; int coff;
};
struct GemmBatch { GemmJob j[6]; };

__device__ inline int swz(int row, int slot) {   // short-index into [row][64] layout
    return row * 64 + ((slot ^ (row & 7)) << 3);
}

__global__ __launch_bounds__(256) void k_dots_gemm(GemmBatch batch,
        const float* __restrict__ embs,
        const float* __restrict__ uA, const float* __restrict__ uB,
        float* __restrict__ dA, float* __restrict__ dB)
{
    __shared__ short Als[2][64 * 64];      // 16 KB
    __shared__ short Bls[2][64 * 64];      // 16 KB
    int bx = blockIdx.x;
    if (bx < 1024) {
        int tok = bx, t = threadIdx.x;
        const float* e = embs + (size_t)tok * kH;
        float s[8] = {0, 0, 0, 0, 0, 0, 0, 0};
        for (int h = t; h < kH; h += 256) {
            float x = e[h];
#pragma unroll
            for (int j = 0; j < 4; j++) {
                s[j]     += x * uA[j * kH + h];
                s[4 + j] += x * uB[j * kH + h];
            }
        }
#pragma unroll
        for (int off = 32; off; off >>= 1)
#pragma unroll
            for (int j = 0; j < 8; j++) s[j] += __shfl_down(s[j], off, 64);
        float(*red)[4] = (float(*)[4])&Als[0][0];
        int wid = t >> 6;
        if ((t & 63) == 0) {
#pragma unroll
            for (int j = 0; j < 8; j++) red[j][wid] = s[j];
        }
        __syncthreads();
        if (t == 0) {
#pragma unroll
            for (int j = 0; j < 4; j++) {
                dA[j * 1024 + tok] = red[j][0] + red[j][1] + red[j][2] + red[j][3];
                dB[j * 1024 + tok] = red[4 + j][0] + red[4 + j][1] + red[4 + j][2] + red[4 + j][3];
            }
        }
        return;
    }
    // ---- GEMM tile: flat index -> (job, m-tile, n-tile) ----
    int g = bx - 1024;
    int jz, mx, ny;
    if (g < 48)       { jz = g / 12;            mx = 0;              ny = g % 12; }
    else if (g < 240) { jz = 4;                 mx = (g - 48) / 12;  ny = (g - 48) % 12; }
    else              { jz = 5;                 mx = (g - 240) / 12; ny = (g - 240) % 12; }
    GemmJob jb = batch.j[jz];

    int tid = threadIdx.x;
    int m0 = mx * 64;
    int n0 = ny * 64;
    int w = tid >> 6, lane = tid & 63;
    int wm = (w >> 1) * 32, wn = (w & 1) * 32;   // 2M x 2N waves, each 32x32
    int lrow = lane & 15, lhi = lane >> 4;
    int srow = tid >> 2, sc0 = tid & 3;          // chunks sc0 and sc0+4
    int K = jb.K;
    int T = K >> 6;

    f32x4 zero4 = {0.f, 0.f, 0.f, 0.f};
    f32x4 acc[2][2];
#pragma unroll
    for (int i = 0; i < 2; i++)
#pragma unroll
        for (int j = 0; j < 2; j++) acc[i][j] = zero4;

    bf16x8 pa[2], pb[2];

#define LOADT(k0)                                                                 \
    {                                                                             \
        _Pragma("unroll")                                                         \
        for (int q = 0; q < 2; q++) {                                             \
            bf16x8 va;                                                            \
            _Pragma("unroll") for (int z = 0; z < 8; z++) va[z] = 0;              \
            if (m0 + srow < jb.M)                                                 \
                va = *reinterpret_cast<const bf16x8*>(                            \
                    jb.A + (size_t)(m0 + srow) * K + (k0) + (sc0 + q * 4) * 8);   \
            pa[q] = va;                                                           \
            pb[q] = *reinterpret_cast<const bf16x8*>(                             \
                jb.Wt + (size_t)(n0 + srow) * K + (k0) + (sc0 + q * 4) * 8);      \
        }                                                                         \
    }
#define STORET(buf)                                                               \
    {                                                                             \
        _Pragma("unroll")                                                         \
        for (int q = 0; q < 2; q++) {                                             \
            *reinterpret_cast<bf16x8*>(&Als[buf][swz(srow, sc0 + q * 4)]) = pa[q];\
            *reinterpret_cast<bf16x8*>(&Bls[buf][swz(srow, sc0 + q * 4)]) = pb[q];\
        }                                                                         \
    }

    LOADT(0);
    STORET(0);
    __syncthreads();
    int cur = 0;
    for (int t = 0; t < T; t++) {
        if (t + 1 < T) LOADT((t + 1) << 6);
#pragma unroll
        for (int sub = 0; sub < 2; sub++) {
            bf16x8 af[2], bg[2];
#pragma unroll
            for (int i = 0; i < 2; i++) {
                af[i] = *reinterpret_cast<const bf16x8*>(
                    &Als[cur][swz(wm + i * 16 + lrow, sub * 4 + lhi)]);
                bg[i] = *reinterpret_cast<const bf16x8*>(
                    &Bls[cur][swz(wn + i * 16 + lrow, sub * 4 + lhi)]);
            }
#pragma unroll
            for (int i = 0; i < 2; i++)
#pragma unroll
                for (int j = 0; j < 2; j++)
                    acc[i][j] = __builtin_amdgcn_mfma_f32_16x16x32_bf16(af[i], bg[j], acc[i][j], 0, 0, 0);
        }
        if (t + 1 < T) STORET(cur ^ 1);
        __syncthreads();
        cur ^= 1;
    }
#undef LOADT
#undef STORET

#pragma unroll
    for (int i = 0; i < 2; i++) {
#pragma unroll
        for (int j = 0; j < 2; j++) {
            int n = n0 + wn + j * 16 + lrow;
            float bi = jb.bias[n];
#pragma unroll
            for (int q = 0; q < 4; q++) {
                int m = m0 + wm + i * 16 + lhi * 4 + q;
                if (m < jb.M) {
                    float val = acc[i][j][q] + bi;
                    if (jb.rowmask) val = (jb.rowmask[m] != 0.f) ? val : 0.f;
                    if (jb.C)   jb.C[(size_t)m * jb.ldc + jb.coff + n] = val;
                    if (jb.Cbf) jb.Cbf[(size_t)m * jb.ldc + jb.coff + n] = f2bf(val);
                }
            }
        }
    }
}

// ---- 3. attention: scores (VALU-only tanh) + softmax + c-dots; r==0 scan->t ----
__global__ __launch_bounds__(512) void k_score(const u16* __restrict__ tokpB,
        const float* __restrict__ relpf, const float* __restrict__ relpb,
        const float* __restrict__ hgpf, const float* __restrict__ hgpb,
        const float* __restrict__ V_w, const float* __restrict__ V_b,
        const float* __restrict__ dd, const float* __restrict__ dA,
        const float* __restrict__ dB, const float* __restrict__ cc,
        const float* __restrict__ logits,
        float* __restrict__ c4, float* __restrict__ c5,
        float* __restrict__ c6, float* __restrict__ c7,
        float* __restrict__ t4, float* __restrict__ t5,
        float* __restrict__ t6, float* __restrict__ t7)
{
    int idx = blockIdx.x;            // 512
    int which = idx >> 8, b = (idx >> 6) & 3, r = idx & 63;
    int tid = threadIdx.x;
    int wid = tid >> 6, lane = tid & 63;
    int h0 = lane * 12;
    const float* relp = (which ? relpb : relpf) + (size_t)r * kH + h0;
    const float* hgp  = (which ? hgpb : hgpf) + (size_t)b * kH + h0;
    const float* vw   = V_w + h0;

    __shared__ float sc[kL];
    __shared__ float red2[2][8];
    __shared__ float PA0[kL], PA1[kL], pv0[kL], pv1[kL];
    __shared__ int warr[4];
    __shared__ int itot[4];
    __shared__ float ftot0[4], ftot1[4];

    float av[12], wv12[12];
#pragma unroll
    for (int j = 0; j < 12; j++) {
        av[j] = relp[j] + hgp[j];
        wv12[j] = vw[j];
    }
    float vb = V_b[0];
    const u16* base = tokpB + ((size_t)which * (kB * kL) + b * kL) * kH + h0;

    int l0 = wid * 32;
    bf16x4 t0 = *reinterpret_cast<const bf16x4*>(base + (size_t)l0 * kH);
    bf16x4 t1 = *reinterpret_cast<const bf16x4*>(base + (size_t)l0 * kH + 4);
    bf16x4 t2 = *reinterpret_cast<const bf16x4*>(base + (size_t)l0 * kH + 8);
    for (int l = l0; l < l0 + 32; l++) {
        bf16x4 n0, n1, n2;
        if (l + 1 < l0 + 32) {
            const u16* nrow = base + (size_t)(l + 1) * kH;
            n0 = *reinterpret_cast<const bf16x4*>(nrow);
            n1 = *reinterpret_cast<const bf16x4*>(nrow + 4);
            n2 = *reinterpret_cast<const bf16x4*>(nrow + 8);
        }
        float acc = 0.f;
#pragma unroll
        for (int j = 0; j < 4; j++) {
            acc = fmaf(wv12[j],     tanh_valu(bf2f((u16)t0[j]) + av[j]),     acc);
            acc = fmaf(wv12[4 + j], tanh_valu(bf2f((u16)t1[j]) + av[4 + j]), acc);
            acc = fmaf(wv12[8 + j], tanh_valu(bf2f((u16)t2[j]) + av[8 + j]), acc);
        }
#pragma unroll
        for (int off = 32; off; off >>= 1) acc += __shfl_xor(acc, off, 64);
        if (lane == 0) sc[l] = acc + vb;
        t0 = n0; t1 = n1; t2 = n2;
    }
    __syncthreads();

    // softmax over sc[0..255] + c-dots (A never materialized)
    int l = tid & 255;
    bool act = tid < 256;
    float x = act ? sc[l] : -3.4e38f;
    float m = x;
#pragma unroll
    for (int off = 32; off; off >>= 1) m = fmaxf(m, __shfl_xor(m, off, 64));
    if (lane == 0) red2[0][wid] = m;
    __syncthreads();
    m = fmaxf(fmaxf(red2[0][0], red2[0][1]), fmaxf(red2[0][2], red2[0][3]));
    float p = act ? __expf(x - m) : 0.f;
    float s = p;
#pragma unroll
    for (int off = 32; off; off >>= 1) s += __shfl_xor(s, off, 64);
    __syncthreads();
    if (lane == 0) red2[0][wid] = s;
    __syncthreads();
    s = red2[0][0] + red2[0][1] + red2[0][2] + red2[0][3];
    float a = p / s;
    const float* ddA = dd + (size_t)(which ? 2 : 0) * 1024 + b * 256;
    const float* ddB = dd + (size_t)(which ? 3 : 1) * 1024 + b * 256;
    float q0 = act ? a * ddA[l] : 0.f;
    float q1 = act ? a * ddB[l] : 0.f;
#pragma unroll
    for (int off = 32; off; off >>= 1) {
        q0 += __shfl_xor(q0, off, 64);
        q1 += __shfl_xor(q1, off, 64);
    }
    __syncthreads();
    if (lane == 0) { red2[0][wid] = q0; red2[1][wid] = q1; }
    __syncthreads();
    if (tid == 0) {
        float cv0 = red2[0][0] + red2[0][1] + red2[0][2] + red2[0][3];
        float cv1 = red2[1][0] + red2[1][1] + red2[1][2] + red2[1][3];
        int loc = b * kR + r;
        if (which) { c6[loc] = cv0; c7[loc] = cv1; }
        else       { c4[loc] = cv0; c5[loc] = cv1; }
    }

    if (r != 0) return;
    // ---- r==0 blocks only: shuffle-scan -> t vectors (coalesced writes) ----
    int p0 = which ? 2 : 0, p1 = p0 + 1;
    const float* slog = logits + (which ? OFF_BOS : OFF_FSS) + (size_t)b * kL;
    const float* elog = logits + (which ? OFF_BOE : OFF_FSE) + (size_t)b * kL;
    bool st = false;
    int smv = kL;
    float a0v = 0.f, a1v = 0.f;
    if (act) {
        st = slog[l] > 0.f;                       // sigmoid(x)>0.5 <=> x>0
        smv = (elog[l] > 0.f) ? l : kL;
        a0v = dA[(size_t)p0 * 1024 + b * 256 + l];
        a1v = dA[(size_t)p1 * 1024 + b * 256 + l];
    }
    int sv = smv;
#pragma unroll
    for (int off2 = 1; off2 < 64; off2 <<= 1) {
        int o = __shfl_down(sv, off2, 64);
        if (lane + off2 < 64) sv = min(sv, o);
    }
    if (act && lane == 0) warr[wid] = sv;
    __syncthreads();
    int next_end = sv;
    if (act)
        for (int w2 = wid + 1; w2 < 4; w2++) next_end = min(next_end, warr[w2]);
    int validi = (act && st && next_end < kL) ? 1 : 0;
    int px = validi;
    float q0v = a0v, q1v = a1v;
#pragma unroll
    for (int off2 = 1; off2 < 64; off2 <<= 1) {
        int oi = __shfl_up(px, off2, 64);
        float o0 = __shfl_up(q0v, off2, 64);
        float o1 = __shfl_up(q1v, off2, 64);
        if (lane >= off2) { px += oi; q0v += o0; q1v += o1; }
    }
    if (act && lane == 63) { itot[wid] = px; ftot0[wid] = q0v; ftot1[wid] = q1v; }
    __syncthreads();
    if (act) {
        for (int w2 = 0; w2 < wid; w2++) { px += itot[w2]; q0v += ftot0[w2]; q1v += ftot1[w2]; }
        PA0[l] = q0v; PA1[l] = q1v;
        pv0[l] = 0.f; pv1[l] = 0.f;
    }
    __syncthreads();
    if (validi) {
        int j = next_end;
        int rk = px - 1;
        float inv = 1.f / (float)(j - l + 1);
        float lo0 = l ? PA0[l - 1] : 0.f;
        float lo1 = l ? PA1[l - 1] : 0.f;
        pv0[rk] = (PA0[j] - lo0) * inv;
        pv1[rk] = (PA1[j] - lo1) * inv;
    }
    __syncthreads();
    if (act) {
        int num = itot[0] + itot[1] + itot[2] + itot[3];
        float tv0 = ((l < num) ? (pv0[l] + cc[p0]) : 0.f)
                  + dB[(size_t)p0 * 1024 + b * 256 + l] + cc[4 + p0];
        float tv1 = ((l < num) ? (pv1[l] + cc[p1]) : 0.f)
                  + dB[(size_t)p1 * 1024 + b * 256 + l] + cc[4 + p1];
        if (which) { t6[b * kL + l] = tv0; t7[b * kL + l] = tv1; }
        else       { t4[b * kL + l] = tv0; t5[b * kL + l] = tv1; }
    }
}

// ---- 4. final broadcast-add (fully coalesced) ----
__global__ __launch_bounds__(64) void k_final(const float* __restrict__ t4,
        const float* __restrict__ t5, const float* __restrict__ t6,
        const float* __restrict__ t7, const float* __restrict__ c4,
        const float* __restrict__ c5, const float* __restrict__ c6,
        const float* __restrict__ c7, const float* __restrict__ fc_b,
        float* __restrict__ out)
{
    int which = blockIdx.x >> 10;
    int t = blockIdx.x & 1023;
    int b = t >> 8;
    int r = threadIdx.x;
    if (!which) {
        out[OFF_FOS + (size_t)t * kR + r] = t4[t] + c4[b * kR + r] + fc_b[4];
        out[OFF_FOE + (size_t)t * kR + r] = t5[t] + c5[b * kR + r] + fc_b[5];
    } else {
        out[OFF_BSS + (size_t)t * kR + r] = t6[t] + c6[b * kR + r] + fc_b[6];
        out[OFF_BSE + (size_t)t * kR + r] = t7[t] + c7[b * kR + r] + fc_b[7];
    }
}

extern "C" void kernel_launch(void* const* d_in, const int* in_sizes, int n_in,
                              void* d_out, int out_size, void* d_ws, size_t ws_size,
                              hipStream_t stream)
{
    const float* embs       = (const float*)d_in[0];
    const float* h_gs       = (const float*)d_in[1];
    const float* rel_embs   = (const float*)d_in[2];
    const float* rel_transe = (const float*)d_in[3];
    const float* fc_w       = (const float*)d_in[4];
    const float* fc_b       = (const float*)d_in[5];
    const float* Wm         = (const float*)d_in[6];
    const float* Wb         = (const float*)d_in[7];
    const float* V_w        = (const float*)d_in[8];
    const float* V_b        = (const float*)d_in[9];
    const float* rproj_w    = (const float*)d_in[10];
    const float* rproj_b    = (const float*)d_in[11];
    float* out = (float*)d_out;
    float* ws  = (float*)d_ws;

    u16* WtAll   = (u16*)(ws + WS_WTALL);
    u16* embsB   = (u16*)(ws + WS_EMBSB);
    u16* relembB = (u16*)(ws + WS_RELEMBB);
    u16* hgsB    = (u16*)(ws + WS_HGSB);
    u16* brelB   = (u16*)(ws + WS_BRELB);
    u16* tokpB   = (u16*)(ws + WS_TOKPB);
    float* relpf = ws + WS_RELPF;
    float* relpb = ws + WS_RELPB;
    float* hgpf  = ws + WS_HGPF;
    float* hgpb  = ws + WS_HGPB;
    float* dd    = ws + WS_DD;
    float* dA    = ws + WS_DA;
    float* dB    = ws + WS_DB;
    float* uA    = ws + WS_UA;
    float* uB    = ws + WS_UB;
    float* cc    = ws + WS_CC;
    float* c4 = ws + WS_C4; float* c5 = ws + WS_C5;
    float* c6 = ws + WS_C6; float* c7 = ws + WS_C7;
    float* t4 = ws + WS_T4; float* t5 = ws + WS_T5;
    float* t6 = ws + WS_T6; float* t7 = ws + WS_T7;

    // 1. mega-prep (everything depending only on inputs)
    k_prep_all<<<2796, 256, 0, stream>>>(embs, rel_embs, h_gs, rel_transe,
        fc_w, fc_b, Wm, Wb, rproj_w, rproj_b,
        out, embsB, relembB, hgsB, brelB, WtAll, uA, uB, cc, dd);

    // 2. per-token uA/uB dots (coalesced) + gemmA
    {
        GemmBatch bt;
        bt.j[0] = { relembB, WtAll + 2 * HH, Wb + 2 * kH, relpf, nullptr, nullptr, kR, kH, kH, 0 };
        bt.j[1] = { hgsB,    WtAll + 3 * HH, Wb + 3 * kH, hgpf,  nullptr, nullptr, kB, kH, kH, 0 };
        bt.j[2] = { hgsB,    WtAll + 6 * HH, Wb + 6 * kH, hgpb,  nullptr, nullptr, kB, kH, kH, 0 };
        bt.j[3] = { brelB,   WtAll + 5 * HH, Wb + 5 * kH, relpb, nullptr, nullptr, kR, kH, kH, 0 };
        bt.j[4] = { embsB,   WtAll + 4 * HH, Wb + 4 * kH, nullptr, tokpB,            nullptr, kB * kL, kH, kH, 0 };
        bt.j[5] = { embsB,   WtAll + 7 * HH, Wb + 7 * kH, nullptr, tokpB + (size_t)kB * kL * kH, nullptr, kB * kL, kH, kH, 0 };
        k_dots_gemm<<<1456, 256, 0, stream>>>(bt, embs, uA, uB, dA, dB);
    }

    // 3. fused scores + softmax + c-dots (+ scan/t on r==0 blocks)
    k_score<<<512, 512, 0, stream>>>(tokpB, relpf, relpb, hgpf, hgpb, V_w, V_b,
                                     dd, dA, dB, cc, out,
                                     c4, c5, c6, c7, t4, t5, t6, t7);

    // 4. final coalesced broadcast-add
    k_final<<<2 * kB * kL, 64, 0, stream>>>(t4, t5, t6, t7, c4, c5, c6, c7, fc_b, out);
}

// Round 19
// 68.362 us; speedup vs baseline: 1.1737x; 1.1737x over previous
//
#include <hip/hip_runtime.h>
#include <cstddef>

using u16 = unsigned short;
typedef __attribute__((ext_vector_type(8))) short bf16x8;
typedef __attribute__((ext_vector_type(4))) short bf16x4;
typedef __attribute__((ext_vector_type(4))) float f32x4;

constexpr int kB = 4, kL = 256, kR = 64, kH = 768, kTE = 100;
constexpr size_t HH = (size_t)kH * kH;

// ---- output offsets (floats) in return order ----
constexpr size_t OFF_FSS = 0;
constexpr size_t OFF_FSE = OFF_FSS + kB * kL;
constexpr size_t OFF_FOS = OFF_FSE + kB * kL;
constexpr size_t OFF_FOE = OFF_FOS + (size_t)kB * kL * kR;
constexpr size_t OFF_BOS = OFF_FOE + (size_t)kB * kL * kR;
constexpr size_t OFF_BOE = OFF_BOS + kB * kL;
constexpr size_t OFF_BSS = OFF_BOE + kB * kL;
constexpr size_t OFF_BSE = OFF_BSS + (size_t)kB * kL * kR;

// ---- workspace layout (float units), no aliasing ----
constexpr size_t WS_WTALL   = 0;                                   // 10xHH u16 (2..7 used)
constexpr size_t WS_EMBSB   = WS_WTALL   + 10 * HH / 2;            // 1024x768 u16
constexpr size_t WS_RELEMBB = WS_EMBSB   + (1024 * 768) / 2;       // 64x768 u16
constexpr size_t WS_HGSB    = WS_RELEMBB + (64 * 768) / 2;         // 4x768 u16
constexpr size_t WS_BRELB   = WS_HGSB    + (4 * 768) / 2;          // 64x768 u16
constexpr size_t WS_TOKPB   = WS_BRELB   + (64 * 768) / 2;         // 2x1024x768 u16
constexpr size_t WS_RELPF   = WS_TOKPB   + (2 * 1024 * 768) / 2;   // 64x768 f32
constexpr size_t WS_RELPB   = WS_RELPF   + 64 * 768;
constexpr size_t WS_HGPF    = WS_RELPB   + 64 * 768;               // 4x768 f32
constexpr size_t WS_HGPB    = WS_HGPF    + 4 * 768;
constexpr size_t WS_DD      = WS_HGPB    + 4 * 768;                // 4x1024 f32 (fc dots)
constexpr size_t WS_DA      = WS_DD      + 4 * 1024;               // 4x1024 f32 (uA dots)
constexpr size_t WS_DB      = WS_DA      + 4 * 1024;               // 4x1024 f32 (uB dots)
constexpr size_t WS_UA      = WS_DB      + 4 * 1024;               // 4x768 f32
constexpr size_t WS_UB      = WS_UA      + 4 * 768;                // 4x768 f32
constexpr size_t WS_CC      = WS_UB      + 4 * 768;                // 8 f32
constexpr size_t WS_C4      = WS_CC      + 8;                      // 256 each
constexpr size_t WS_C5      = WS_C4 + 256;
constexpr size_t WS_C6      = WS_C5 + 256;
constexpr size_t WS_C7      = WS_C6 + 256;
constexpr size_t WS_T4      = WS_C7 + 256;                         // 1024 each
constexpr size_t WS_T5      = WS_T4 + 1024;
constexpr size_t WS_T6      = WS_T5 + 1024;
constexpr size_t WS_T7      = WS_T6 + 1024;

__device__ inline float fast_rcp(float x) {
#if __has_builtin(__builtin_amdgcn_rcpf)
    return __builtin_amdgcn_rcpf(x);
#else
    return 1.f / x;
#endif
}
__device__ inline float fast_exp2(float x) {
#if __has_builtin(__builtin_amdgcn_exp2f)
    return __builtin_amdgcn_exp2f(x);
#else
    return __exp2f(x);
#endif
}
__device__ inline u16 f2bf(float x) {   // RNE
    union { float f; unsigned u; } v; v.f = x;
    unsigned r = v.u + 0x7FFFu + ((v.u >> 16) & 1u);
    return (u16)(r >> 16);
}
__device__ inline float bf2f(u16 x) {
    union { unsigned u; float f; } v; v.u = ((unsigned)x) << 16;
    return v.f;
}

// ---- 1. mega-prep ----
__global__ __launch_bounds__(256) void k_prep_all(
        const float* __restrict__ embs, const float* __restrict__ rel_embs,
        const float* __restrict__ h_gs, const float* __restrict__ rel_transe,
        const float* __restrict__ fc_w, const float* __restrict__ fc_b,
        const float* __restrict__ Wm, const float* __restrict__ Wb,
        const float* __restrict__ rproj_w, const float* __restrict__ rproj_b,
        float* __restrict__ out, u16* __restrict__ embsB,
        u16* __restrict__ relembB, u16* __restrict__ hgsB, u16* __restrict__ brelB,
        u16* __restrict__ WtAll,
        float* __restrict__ uA, float* __restrict__ uB, float* __restrict__ cc,
        float* __restrict__ dd)
{
    __shared__ float sh[64 * 65];
    int bx = blockIdx.x, t = threadIdx.x;
    if (bx < 1024) {
        int tok = bx;
        const float* e = embs + (size_t)tok * kH;
        float s[8] = {0, 0, 0, 0, 0, 0, 0, 0};
        for (int h = t; h < kH; h += 256) {
            float x = e[h];
            embsB[(size_t)tok * kH + h] = f2bf(x);
#pragma unroll
            for (int j = 0; j < 8; j++) s[j] += x * fc_w[j * kH + h];
        }
#pragma unroll
        for (int off = 32; off; off >>= 1)
#pragma unroll
            for (int j = 0; j < 8; j++) s[j] += __shfl_down(s[j], off, 64);
        float(*red)[4] = (float(*)[4])sh;
        int wid = t >> 6;
        if ((t & 63) == 0) {
#pragma unroll
            for (int j = 0; j < 8; j++) red[j][wid] = s[j];
        }
        __syncthreads();
        if (t == 0) {
            float r[8];
#pragma unroll
            for (int j = 0; j < 8; j++) r[j] = red[j][0] + red[j][1] + red[j][2] + red[j][3];
            out[OFF_FSS + tok] = r[0] + fc_b[0];
            out[OFF_FSE + tok] = r[1] + fc_b[1];
            out[OFF_BOS + tok] = r[2] + fc_b[2];
            out[OFF_BOE + tok] = r[3] + fc_b[3];
            dd[0 * 1024 + tok] = r[4];
            dd[1 * 1024 + tok] = r[5];
            dd[2 * 1024 + tok] = r[6];
            dd[3 * 1024 + tok] = r[7];
        }
    } else if (bx < 1888) {
        int px = bx - 1024;
        int mi = 2 + px / 144, tile = px % 144;
        int kt = (tile / 12) * 64, nt = (tile % 12) * 64;
        const float* src = Wm + (size_t)mi * HH;
        u16* dst = WtAll + (size_t)mi * HH;
        float(*tl)[65] = (float(*)[65])sh;
        int r = t >> 2, cq = (t & 3) * 16;
        int row = kt + r;
#pragma unroll
        for (int q = 0; q < 4; q++) {
            float4 v = *(const float4*)(src + (size_t)row * kH + nt + cq + q * 4);
            tl[r][cq + q * 4 + 0] = v.x;
            tl[r][cq + q * 4 + 1] = v.y;
            tl[r][cq + q * 4 + 2] = v.z;
            tl[r][cq + q * 4 + 3] = v.w;
        }
        __syncthreads();
        u16* drow = dst + (size_t)(nt + r) * kH + kt + cq;
#pragma unroll
        for (int j = 0; j < 16; j++) drow[j] = f2bf(tl[cq + j][r]);
    } else if (bx < 2656) {
        int gx = bx - 1888;
        int p = gx / 192;
        int wid = t >> 6, lane = t & 63;
        int row = (gx % 192) * 4 + wid;
        const int wmI[4] = {0, 1, 8, 9};
        const float* W  = Wm + (size_t)wmI[p] * HH + (size_t)row * kH;
        const float* wa = fc_w + (size_t)((p & 1) ? 6 : 4) * kH;
        const float* wb = wa + kH;
        float sa = 0.f, sb = 0.f;
        for (int c = lane; c < kH; c += 64) {
            float wv = W[c];
            sa += wv * wa[c];
            sb += wv * wb[c];
        }
#pragma unroll
        for (int off = 32; off; off >>= 1) {
            sa += __shfl_xor(sa, off, 64);
            sb += __shfl_xor(sb, off, 64);
        }
        if (lane == 0) {
            if (p < 2) {
                uA[(2 * p) * kH + row]     = sa;
                uA[(2 * p + 1) * kH + row] = sb;
            } else {
                int q = p - 2;
                uB[(2 * q) * kH + row]     = sa + wa[row];
                uB[(2 * q + 1) * kH + row] = sb + wb[row];
            }
        }
    } else if (bx < 2720) {
        int r = bx - 2656;
        for (int h = t; h < kH; h += 256) relembB[r * kH + h] = f2bf(rel_embs[r * kH + h]);
    } else if (bx < 2724) {
        int r = bx - 2720;
        for (int h = t; h < kH; h += 256) hgsB[r * kH + h] = f2bf(h_gs[r * kH + h]);
    } else if (bx < 2788) {
        int r = bx - 2724;
        if (t < kTE) sh[t] = rel_transe[r * kTE + t];
        __syncthreads();
        float a0 = rproj_b[t], a1 = rproj_b[t + 256], a2 = rproj_b[t + 512];
        for (int k = 0; k < kTE; k++) {
            float rv = sh[k];
            const float* wr = rproj_w + (size_t)k * kH;
            a0 = fmaf(rv, wr[t], a0);
            a1 = fmaf(rv, wr[t + 256], a1);
            a2 = fmaf(rv, wr[t + 512], a2);
        }
        brelB[r * kH + t]       = f2bf(a0);
        brelB[r * kH + t + 256] = f2bf(a1);
        brelB[r * kH + t + 512] = f2bf(a2);
    } else {
        int j = bx - 2788;
        const int wbI[8] = {0, 0, 1, 1, 8, 8, 9, 9};
        const int fcI[8] = {4, 5, 6, 7, 4, 5, 6, 7};
        const float* wb = Wb + (size_t)wbI[j] * kH;
        const float* w  = fc_w + (size_t)fcI[j] * kH;
        float s = 0.f;
        for (int h = t; h < kH; h += 256) s += wb[h] * w[h];
#pragma unroll
        for (int off = 32; off; off >>= 1) s += __shfl_down(s, off, 64);
        int wid = t >> 6;
        if ((t & 63) == 0) sh[wid] = s;
        __syncthreads();
        if (t == 0) cc[j] = sh[0] + sh[1] + sh[2] + sh[3];
    }
}

// ---- 2. per-token uA/uB dots (coalesced) + batched MFMA GEMM ----
struct GemmJob {
    const u16* A; const u16* Wt; const float* bias;
    float* C; u16* Cbf; const float* rowmask;
    int M; int K; int ldc; int coff;
};
struct GemmBatch { GemmJob j[6]; };

__device__ inline int swz(int row, int slot) {   // short-index into [row][64] layout
    return row * 64 + ((slot ^ (row & 7)) << 3);
}

__global__ __launch_bounds__(256) void k_dots_gemm(GemmBatch batch,
        const float* __restrict__ embs,
        const float* __restrict__ uA, const float* __restrict__ uB,
        float* __restrict__ dA, float* __restrict__ dB)
{
    __shared__ short Als[2][64 * 64];      // 16 KB
    __shared__ short Bls[2][64 * 64];      // 16 KB
    int bx = blockIdx.x;
    if (bx < 1024) {
        int tok = bx, t = threadIdx.x;
        const float* e = embs + (size_t)tok * kH;
        float s[8] = {0, 0, 0, 0, 0, 0, 0, 0};
        for (int h = t; h < kH; h += 256) {
            float x = e[h];
#pragma unroll
            for (int j = 0; j < 4; j++) {
                s[j]     += x * uA[j * kH + h];
                s[4 + j] += x * uB[j * kH + h];
            }
        }
#pragma unroll
        for (int off = 32; off; off >>= 1)
#pragma unroll
            for (int j = 0; j < 8; j++) s[j] += __shfl_down(s[j], off, 64);
        float(*red)[4] = (float(*)[4])&Als[0][0];
        int wid = t >> 6;
        if ((t & 63) == 0) {
#pragma unroll
            for (int j = 0; j < 8; j++) red[j][wid] = s[j];
        }
        __syncthreads();
        if (t == 0) {
#pragma unroll
            for (int j = 0; j < 4; j++) {
                dA[j * 1024 + tok] = red[j][0] + red[j][1] + red[j][2] + red[j][3];
                dB[j * 1024 + tok] = red[4 + j][0] + red[4 + j][1] + red[4 + j][2] + red[4 + j][3];
            }
        }
        return;
    }
    // ---- GEMM tile: flat index -> (job, m-tile, n-tile) ----
    int g = bx - 1024;
    int jz, mx, ny;
    if (g < 48)       { jz = g / 12;            mx = 0;              ny = g % 12; }
    else if (g < 240) { jz = 4;                 mx = (g - 48) / 12;  ny = (g - 48) % 12; }
    else              { jz = 5;                 mx = (g - 240) / 12; ny = (g - 240) % 12; }
    GemmJob jb = batch.j[jz];

    int tid = threadIdx.x;
    int m0 = mx * 64;
    int n0 = ny * 64;
    int w = tid >> 6, lane = tid & 63;
    int wm = (w >> 1) * 32, wn = (w & 1) * 32;   // 2M x 2N waves, each 32x32
    int lrow = lane & 15, lhi = lane >> 4;
    int srow = tid >> 2, sc0 = tid & 3;          // chunks sc0 and sc0+4
    int K = jb.K;
    int T = K >> 6;

    f32x4 zero4 = {0.f, 0.f, 0.f, 0.f};
    f32x4 acc[2][2];
#pragma unroll
    for (int i = 0; i < 2; i++)
#pragma unroll
        for (int j = 0; j < 2; j++) acc[i][j] = zero4;

    bf16x8 pa[2], pb[2];

#define LOADT(k0)                                                                 \
    {                                                                             \
        _Pragma("unroll")                                                         \
        for (int q = 0; q < 2; q++) {                                             \
            bf16x8 va;                                                            \
            _Pragma("unroll") for (int z = 0; z < 8; z++) va[z] = 0;              \
            if (m0 + srow < jb.M)                                                 \
                va = *reinterpret_cast<const bf16x8*>(                            \
                    jb.A + (size_t)(m0 + srow) * K + (k0) + (sc0 + q * 4) * 8);   \
            pa[q] = va;                                                           \
            pb[q] = *reinterpret_cast<const bf16x8*>(                             \
                jb.Wt + (size_t)(n0 + srow) * K + (k0) + (sc0 + q * 4) * 8);      \
        }                                                                         \
    }
#define STORET(buf)                                                               \
    {                                                                             \
        _Pragma("unroll")                                                         \
        for (int q = 0; q < 2; q++) {                                             \
            *reinterpret_cast<bf16x8*>(&Als[buf][swz(srow, sc0 + q * 4)]) = pa[q];\
            *reinterpret_cast<bf16x8*>(&Bls[buf][swz(srow, sc0 + q * 4)]) = pb[q];\
        }                                                                         \
    }

    LOADT(0);
    STORET(0);
    __syncthreads();
    int cur = 0;
    for (int t = 0; t < T; t++) {
        if (t + 1 < T) LOADT((t + 1) << 6);
#pragma unroll
        for (int sub = 0; sub < 2; sub++) {
            bf16x8 af[2], bg[2];
#pragma unroll
            for (int i = 0; i < 2; i++) {
                af[i] = *reinterpret_cast<const bf16x8*>(
                    &Als[cur][swz(wm + i * 16 + lrow, sub * 4 + lhi)]);
                bg[i] = *reinterpret_cast<const bf16x8*>(
                    &Bls[cur][swz(wn + i * 16 + lrow, sub * 4 + lhi)]);
            }
#pragma unroll
            for (int i = 0; i < 2; i++)
#pragma unroll
                for (int j = 0; j < 2; j++)
                    acc[i][j] = __builtin_amdgcn_mfma_f32_16x16x32_bf16(af[i], bg[j], acc[i][j], 0, 0, 0);
        }
        if (t + 1 < T) STORET(cur ^ 1);
        __syncthreads();
        cur ^= 1;
    }
#undef LOADT
#undef STORET

#pragma unroll
    for (int i = 0; i < 2; i++) {
#pragma unroll
        for (int j = 0; j < 2; j++) {
            int n = n0 + wn + j * 16 + lrow;
            float bi = jb.bias[n];
#pragma unroll
            for (int q = 0; q < 4; q++) {
                int m = m0 + wm + i * 16 + lhi * 4 + q;
                if (m < jb.M) {
                    float val = acc[i][j][q] + bi;
                    if (jb.rowmask) val = (jb.rowmask[m] != 0.f) ? val : 0.f;
                    if (jb.C)   jb.C[(size_t)m * jb.ldc + jb.coff + n] = val;
                    if (jb.Cbf) jb.Cbf[(size_t)m * jb.ldc + jb.coff + n] = f2bf(val);
                }
            }
        }
    }
}

// ---- 3. attention: scores (2-row ILP, trans tanh) + softmax + c-dots; r==0 scan->t ----
__global__ __launch_bounds__(512) void k_score(const u16* __restrict__ tokpB,
        const float* __restrict__ relpf, const float* __restrict__ relpb,
        const float* __restrict__ hgpf, const float* __restrict__ hgpb,
        const float* __restrict__ V_w, const float* __restrict__ V_b,
        const float* __restrict__ dd, const float* __restrict__ dA,
        const float* __restrict__ dB, const float* __restrict__ cc,
        const float* __restrict__ logits,
        float* __restrict__ c4, float* __restrict__ c5,
        float* __restrict__ c6, float* __restrict__ c7,
        float* __restrict__ t4, float* __restrict__ t5,
        float* __restrict__ t6, float* __restrict__ t7)
{
    constexpr float C = 2.8853900817779268f;   // 2*log2(e)
    int idx = blockIdx.x;            // 512
    int which = idx >> 8, b = (idx >> 6) & 3, r = idx & 63;
    int tid = threadIdx.x;
    int wid = tid >> 6, lane = tid & 63;
    int h0 = lane * 12;
    const float* relp = (which ? relpb : relpf) + (size_t)r * kH + h0;
    const float* hgp  = (which ? hgpb : hgpf) + (size_t)b * kH + h0;
    const float* vw   = V_w + h0;

    __shared__ float sc[kL];
    __shared__ float red2[2][8];
    __shared__ float PA0[kL], PA1[kL], pv0[kL], pv1[kL];
    __shared__ int warr[4];
    __shared__ int itot[4];
    __shared__ float ftot0[4], ftot1[4];

    float av2[12], w2[12], wsum = 0.f;
#pragma unroll
    for (int j = 0; j < 12; j++) {
        av2[j] = C * (relp[j] + hgp[j]);
        float wv = vw[j];
        w2[j] = -2.f * wv;
        wsum += wv;
    }
    float vb = V_b[0];
    const u16* base = tokpB + ((size_t)which * (kB * kL) + b * kL) * kH + h0;

    int l0 = wid * 32;
    // process two rows per iteration: independent acc chains double ILP and
    // give the trans unit 24 independent exp/rcp per iteration to pipeline.
    for (int l = l0; l < l0 + 32; l += 2) {
        const u16* row0 = base + (size_t)l * kH;
        const u16* row1 = row0 + kH;
        bf16x4 x0 = *reinterpret_cast<const bf16x4*>(row0);
        bf16x4 x1 = *reinterpret_cast<const bf16x4*>(row0 + 4);
        bf16x4 x2 = *reinterpret_cast<const bf16x4*>(row0 + 8);
        bf16x4 y0 = *reinterpret_cast<const bf16x4*>(row1);
        bf16x4 y1 = *reinterpret_cast<const bf16x4*>(row1 + 4);
        bf16x4 y2 = *reinterpret_cast<const bf16x4*>(row1 + 8);
        float acc0 = wsum, acc1 = wsum;
#pragma unroll
        for (int j = 0; j < 4; j++) {
            float e0 = fast_exp2(fmaf(bf2f((u16)x0[j]), C, av2[j]));
            float f0 = fast_exp2(fmaf(bf2f((u16)y0[j]), C, av2[j]));
            acc0 = fmaf(w2[j], fast_rcp(e0 + 1.f), acc0);
            acc1 = fmaf(w2[j], fast_rcp(f0 + 1.f), acc1);
            float e1 = fast_exp2(fmaf(bf2f((u16)x1[j]), C, av2[4 + j]));
            float f1 = fast_exp2(fmaf(bf2f((u16)y1[j]), C, av2[4 + j]));
            acc0 = fmaf(w2[4 + j], fast_rcp(e1 + 1.f), acc0);
            acc1 = fmaf(w2[4 + j], fast_rcp(f1 + 1.f), acc1);
            float e2 = fast_exp2(fmaf(bf2f((u16)x2[j]), C, av2[8 + j]));
            float f2 = fast_exp2(fmaf(bf2f((u16)y2[j]), C, av2[8 + j]));
            acc0 = fmaf(w2[8 + j], fast_rcp(e2 + 1.f), acc0);
            acc1 = fmaf(w2[8 + j], fast_rcp(f2 + 1.f), acc1);
        }
#pragma unroll
        for (int off = 32; off; off >>= 1) {
            acc0 += __shfl_xor(acc0, off, 64);
            acc1 += __shfl_xor(acc1, off, 64);
        }
        if (lane == 0) { sc[l] = acc0 + vb; sc[l + 1] = acc1 + vb; }
    }
    __syncthreads();

    // softmax over sc[0..255] + c-dots (A never materialized)
    int l = tid & 255;
    bool act = tid < 256;
    float x = act ? sc[l] : -3.4e38f;
    float m = x;
#pragma unroll
    for (int off = 32; off; off >>= 1) m = fmaxf(m, __shfl_xor(m, off, 64));
    if (lane == 0) red2[0][wid] = m;
    __syncthreads();
    m = fmaxf(fmaxf(red2[0][0], red2[0][1]), fmaxf(red2[0][2], red2[0][3]));
    float p = act ? __expf(x - m) : 0.f;
    float s = p;
#pragma unroll
    for (int off = 32; off; off >>= 1) s += __shfl_xor(s, off, 64);
    __syncthreads();
    if (lane == 0) red2[0][wid] = s;
    __syncthreads();
    s = red2[0][0] + red2[0][1] + red2[0][2] + red2[0][3];
    float a = p / s;
    const float* ddA = dd + (size_t)(which ? 2 : 0) * 1024 + b * 256;
    const float* ddB = dd + (size_t)(which ? 3 : 1) * 1024 + b * 256;
    float q0 = act ? a * ddA[l] : 0.f;
    float q1 = act ? a * ddB[l] : 0.f;
#pragma unroll
    for (int off = 32; off; off >>= 1) {
        q0 += __shfl_xor(q0, off, 64);
        q1 += __shfl_xor(q1, off, 64);
    }
    __syncthreads();
    if (lane == 0) { red2[0][wid] = q0; red2[1][wid] = q1; }
    __syncthreads();
    if (tid == 0) {
        float cv0 = red2[0][0] + red2[0][1] + red2[0][2] + red2[0][3];
        float cv1 = red2[1][0] + red2[1][1] + red2[1][2] + red2[1][3];
        int loc = b * kR + r;
        if (which) { c6[loc] = cv0; c7[loc] = cv1; }
        else       { c4[loc] = cv0; c5[loc] = cv1; }
    }

    if (r != 0) return;
    // ---- r==0 blocks only: shuffle-scan -> t vectors (coalesced writes) ----
    int p0 = which ? 2 : 0, p1 = p0 + 1;
    const float* slog = logits + (which ? OFF_BOS : OFF_FSS) + (size_t)b * kL;
    const float* elog = logits + (which ? OFF_BOE : OFF_FSE) + (size_t)b * kL;
    bool st = false;
    int smv = kL;
    float a0v = 0.f, a1v = 0.f;
    if (act) {
        st = slog[l] > 0.f;                       // sigmoid(x)>0.5 <=> x>0
        smv = (elog[l] > 0.f) ? l : kL;
        a0v = dA[(size_t)p0 * 1024 + b * 256 + l];
        a1v = dA[(size_t)p1 * 1024 + b * 256 + l];
    }
    int sv = smv;
#pragma unroll
    for (int off2 = 1; off2 < 64; off2 <<= 1) {
        int o = __shfl_down(sv, off2, 64);
        if (lane + off2 < 64) sv = min(sv, o);
    }
    if (act && lane == 0) warr[wid] = sv;
    __syncthreads();
    int next_end = sv;
    if (act)
        for (int w2 = wid + 1; w2 < 4; w2++) next_end = min(next_end, warr[w2]);
    int validi = (act && st && next_end < kL) ? 1 : 0;
    int px = validi;
    float q0v = a0v, q1v = a1v;
#pragma unroll
    for (int off2 = 1; off2 < 64; off2 <<= 1) {
        int oi = __shfl_up(px, off2, 64);
        float o0 = __shfl_up(q0v, off2, 64);
        float o1 = __shfl_up(q1v, off2, 64);
        if (lane >= off2) { px += oi; q0v += o0; q1v += o1; }
    }
    if (act && lane == 63) { itot[wid] = px; ftot0[wid] = q0v; ftot1[wid] = q1v; }
    __syncthreads();
    if (act) {
        for (int w2 = 0; w2 < wid; w2++) { px += itot[w2]; q0v += ftot0[w2]; q1v += ftot1[w2]; }
        PA0[l] = q0v; PA1[l] = q1v;
        pv0[l] = 0.f; pv1[l] = 0.f;
    }
    __syncthreads();
    if (validi) {
        int j = next_end;
        int rk = px - 1;
        float inv = 1.f / (float)(j - l + 1);
        float lo0 = l ? PA0[l - 1] : 0.f;
        float lo1 = l ? PA1[l - 1] : 0.f;
        pv0[rk] = (PA0[j] - lo0) * inv;
        pv1[rk] = (PA1[j] - lo1) * inv;
    }
    __syncthreads();
    if (act) {
        int num = itot[0] + itot[1] + itot[2] + itot[3];
        float tv0 = ((l < num) ? (pv0[l] + cc[p0]) : 0.f)
                  + dB[(size_t)p0 * 1024 + b * 256 + l] + cc[4 + p0];
        float tv1 = ((l < num) ? (pv1[l] + cc[p1]) : 0.f)
                  + dB[(size_t)p1 * 1024 + b * 256 + l] + cc[4 + p1];
        if (which) { t6[b * kL + l] = tv0; t7[b * kL + l] = tv1; }
        else       { t4[b * kL + l] = tv0; t5[b * kL + l] = tv1; }
    }
}

// ---- 4. final broadcast-add (fully coalesced) ----
__global__ __launch_bounds__(64) void k_final(const float* __restrict__ t4,
        const float* __restrict__ t5, const float* __restrict__ t6,
        const float* __restrict__ t7, const float* __restrict__ c4,
        const float* __restrict__ c5, const float* __restrict__ c6,
        const float* __restrict__ c7, const float* __restrict__ fc_b,
        float* __restrict__ out)
{
    int which = blockIdx.x >> 10;
    int t = blockIdx.x & 1023;
    int b = t >> 8;
    int r = threadIdx.x;
    if (!which) {
        out[OFF_FOS + (size_t)t * kR + r] = t4[t] + c4[b * kR + r] + fc_b[4];
        out[OFF_FOE + (size_t)t * kR + r] = t5[t] + c5[b * kR + r] + fc_b[5];
    } else {
        out[OFF_BSS + (size_t)t * kR + r] = t6[t] + c6[b * kR + r] + fc_b[6];
        out[OFF_BSE + (size_t)t * kR + r] = t7[t] + c7[b * kR + r] + fc_b[7];
    }
}

extern "C" void kernel_launch(void* const* d_in, const int* in_sizes, int n_in,
                              void* d_out, int out_size, void* d_ws, size_t ws_size,
                              hipStream_t stream)
{
    const float* embs       = (const float*)d_in[0];
    const float* h_gs       = (const float*)d_in[1];
    const float* rel_embs   = (const float*)d_in[2];
    const float* rel_transe = (const float*)d_in[3];
    const float* fc_w       = (const float*)d_in[4];
    const float* fc_b       = (const float*)d_in[5];
    const float* Wm         = (const float*)d_in[6];
    const float* Wb         = (const float*)d_in[7];
    const float* V_w        = (const float*)d_in[8];
    const float* V_b        = (const float*)d_in[9];
    const float* rproj_w    = (const float*)d_in[10];
    const float* rproj_b    = (const float*)d_in[11];
    float* out = (float*)d_out;
    float* ws  = (float*)d_ws;

    u16* WtAll   = (u16*)(ws + WS_WTALL);
    u16* embsB   = (u16*)(ws + WS_EMBSB);
    u16* relembB = (u16*)(ws + WS_RELEMBB);
    u16* hgsB    = (u16*)(ws + WS_HGSB);
    u16* brelB   = (u16*)(ws + WS_BRELB);
    u16* tokpB   = (u16*)(ws + WS_TOKPB);
    float* relpf = ws + WS_RELPF;
    float* relpb = ws + WS_RELPB;
    float* hgpf  = ws + WS_HGPF;
    float* hgpb  = ws + WS_HGPB;
    float* dd    = ws + WS_DD;
    float* dA    = ws + WS_DA;
    float* dB    = ws + WS_DB;
    float* uA    = ws + WS_UA;
    float* uB    = ws + WS_UB;
    float* cc    = ws + WS_CC;
    float* c4 = ws + WS_C4; float* c5 = ws + WS_C5;
    float* c6 = ws + WS_C6; float* c7 = ws + WS_C7;
    float* t4 = ws + WS_T4; float* t5 = ws + WS_T5;
    float* t6 = ws + WS_T6; float* t7 = ws + WS_T7;

    // 1. mega-prep (everything depending only on inputs)
    k_prep_all<<<2796, 256, 0, stream>>>(embs, rel_embs, h_gs, rel_transe,
        fc_w, fc_b, Wm, Wb, rproj_w, rproj_b,
        out, embsB, relembB, hgsB, brelB, WtAll, uA, uB, cc, dd);

    // 2. per-token uA/uB dots (coalesced) + gemmA
    {
        GemmBatch bt;
        bt.j[0] = { relembB, WtAll + 2 * HH, Wb + 2 * kH, relpf, nullptr, nullptr, kR, kH, kH, 0 };
        bt.j[1] = { hgsB,    WtAll + 3 * HH, Wb + 3 * kH, hgpf,  nullptr, nullptr, kB, kH, kH, 0 };
        bt.j[2] = { hgsB,    WtAll + 6 * HH, Wb + 6 * kH, hgpb,  nullptr, nullptr, kB, kH, kH, 0 };
        bt.j[3] = { brelB,   WtAll + 5 * HH, Wb + 5 * kH, relpb, nullptr, nullptr, kR, kH, kH, 0 };
        bt.j[4] = { embsB,   WtAll + 4 * HH, Wb + 4 * kH, nullptr, tokpB,            nullptr, kB * kL, kH, kH, 0 };
        bt.j[5] = { embsB,   WtAll + 7 * HH, Wb + 7 * kH, nullptr, tokpB + (size_t)kB * kL * kH, nullptr, kB * kL, kH, kH, 0 };
        k_dots_gemm<<<1456, 256, 0, stream>>>(bt, embs, uA, uB, dA, dB);
    }

    // 3. fused scores + softmax + c-dots (+ scan/t on r==0 blocks)
    k_score<<<512, 512, 0, stream>>>(tokpB, relpf, relpb, hgpf, hgpb, V_w, V_b,
                                     dd, dA, dB, cc, out,
                                     c4, c5, c6, c7, t4, t5, t6, t7);

    // 4. final coalesced broadcast-add
    k_final<<<2 * kB * kL, 64, 0, stream>>>(t4, t5, t6, t7, c4, c5, c6, c7, fc_b, out);
}

// Round 20
// 66.140 us; speedup vs baseline: 1.2132x; 1.0336x over previous
//
#include <hip/hip_runtime.h>
#include <cstddef>

using u16 = unsigned short;
typedef __attribute__((ext_vector_type(8))) short bf16x8;
typedef __attribute__((ext_vector_type(4))) short bf16x4;
typedef __attribute__((ext_vector_type(4))) float f32x4;

constexpr int kB = 4, kL = 256, kR = 64, kH = 768, kTE = 100;
constexpr size_t HH = (size_t)kH * kH;

// ---- output offsets (floats) in return order ----
constexpr size_t OFF_FSS = 0;
constexpr size_t OFF_FSE = OFF_FSS + kB * kL;
constexpr size_t OFF_FOS = OFF_FSE + kB * kL;
constexpr size_t OFF_FOE = OFF_FOS + (size_t)kB * kL * kR;
constexpr size_t OFF_BOS = OFF_FOE + (size_t)kB * kL * kR;
constexpr size_t OFF_BOE = OFF_BOS + kB * kL;
constexpr size_t OFF_BSS = OFF_BOE + kB * kL;
constexpr size_t OFF_BSE = OFF_BSS + (size_t)kB * kL * kR;

// ---- workspace layout (float units), no aliasing ----
constexpr size_t WS_WTALL   = 0;                                   // 10xHH u16 (2..7 used)
constexpr size_t WS_EMBSB   = WS_WTALL   + 10 * HH / 2;            // 1024x768 u16
constexpr size_t WS_RELEMBB = WS_EMBSB   + (1024 * 768) / 2;       // 64x768 u16
constexpr size_t WS_HGSB    = WS_RELEMBB + (64 * 768) / 2;         // 4x768 u16
constexpr size_t WS_BRELB   = WS_HGSB    + (4 * 768) / 2;          // 64x768 u16
constexpr size_t WS_TOKPB   = WS_BRELB   + (64 * 768) / 2;         // 2x1024x768 u16
constexpr size_t WS_RELPF   = WS_TOKPB   + (2 * 1024 * 768) / 2;   // 64x768 f32
constexpr size_t WS_RELPB   = WS_RELPF   + 64 * 768;
constexpr size_t WS_HGPF    = WS_RELPB   + 64 * 768;               // 4x768 f32
constexpr size_t WS_HGPB    = WS_HGPF    + 4 * 768;
constexpr size_t WS_DD      = WS_HGPB    + 4 * 768;                // 4x1024 f32 (fc dots)
constexpr size_t WS_DA      = WS_DD      + 4 * 1024;               // 4x1024 f32 (uA dots)
constexpr size_t WS_DB      = WS_DA      + 4 * 1024;               // 4x1024 f32 (uB dots)
constexpr size_t WS_UA      = WS_DB      + 4 * 1024;               // 4x768 f32
constexpr size_t WS_UB      = WS_UA      + 4 * 768;                // 4x768 f32
constexpr size_t WS_CC      = WS_UB      + 4 * 768;                // 8 f32
constexpr size_t WS_C4      = WS_CC      + 8;                      // 256 each
constexpr size_t WS_C5      = WS_C4 + 256;
constexpr size_t WS_C6      = WS_C5 + 256;
constexpr size_t WS_C7      = WS_C6 + 256;
constexpr size_t WS_T4      = WS_C7 + 256;                         // 1024 each
constexpr size_t WS_T5      = WS_T4 + 1024;
constexpr size_t WS_T6      = WS_T5 + 1024;
constexpr size_t WS_T7      = WS_T6 + 1024;

__device__ inline float fast_rcp(float x) {
#if __has_builtin(__builtin_amdgcn_rcpf)
    return __builtin_amdgcn_rcpf(x);
#else
    return 1.f / x;
#endif
}
__device__ inline float fast_exp2(float x) {
#if __has_builtin(__builtin_amdgcn_exp2f)
    return __builtin_amdgcn_exp2f(x);
#else
    return __exp2f(x);
#endif
}
__device__ inline u16 f2bf(float x) {   // RNE
    union { float f; unsigned u; } v; v.f = x;
    unsigned r = v.u + 0x7FFFu + ((v.u >> 16) & 1u);
    return (u16)(r >> 16);
}
__device__ inline float bf2f(u16 x) {
    union { unsigned u; float f; } v; v.u = ((unsigned)x) << 16;
    return v.f;
}

// ---- 1. mega-prep ----
__global__ __launch_bounds__(256) void k_prep_all(
        const float* __restrict__ embs, const float* __restrict__ rel_embs,
        const float* __restrict__ h_gs, const float* __restrict__ rel_transe,
        const float* __restrict__ fc_w, const float* __restrict__ fc_b,
        const float* __restrict__ Wm, const float* __restrict__ Wb,
        const float* __restrict__ rproj_w, const float* __restrict__ rproj_b,
        float* __restrict__ out, u16* __restrict__ embsB,
        u16* __restrict__ relembB, u16* __restrict__ hgsB, u16* __restrict__ brelB,
        u16* __restrict__ WtAll,
        float* __restrict__ uA, float* __restrict__ uB, float* __restrict__ cc,
        float* __restrict__ dd)
{
    __shared__ float sh[64 * 65];
    int bx = blockIdx.x, t = threadIdx.x;
    if (bx < 1024) {
        int tok = bx;
        const float* e = embs + (size_t)tok * kH;
        float s[8] = {0, 0, 0, 0, 0, 0, 0, 0};
        for (int h = t; h < kH; h += 256) {
            float x = e[h];
            embsB[(size_t)tok * kH + h] = f2bf(x);
#pragma unroll
            for (int j = 0; j < 8; j++) s[j] += x * fc_w[j * kH + h];
        }
#pragma unroll
        for (int off = 32; off; off >>= 1)
#pragma unroll
            for (int j = 0; j < 8; j++) s[j] += __shfl_down(s[j], off, 64);
        float(*red)[4] = (float(*)[4])sh;
        int wid = t >> 6;
        if ((t & 63) == 0) {
#pragma unroll
            for (int j = 0; j < 8; j++) red[j][wid] = s[j];
        }
        __syncthreads();
        if (t == 0) {
            float r[8];
#pragma unroll
            for (int j = 0; j < 8; j++) r[j] = red[j][0] + red[j][1] + red[j][2] + red[j][3];
            out[OFF_FSS + tok] = r[0] + fc_b[0];
            out[OFF_FSE + tok] = r[1] + fc_b[1];
            out[OFF_BOS + tok] = r[2] + fc_b[2];
            out[OFF_BOE + tok] = r[3] + fc_b[3];
            dd[0 * 1024 + tok] = r[4];
            dd[1 * 1024 + tok] = r[5];
            dd[2 * 1024 + tok] = r[6];
            dd[3 * 1024 + tok] = r[7];
        }
    } else if (bx < 1888) {
        int px = bx - 1024;
        int mi = 2 + px / 144, tile = px % 144;
        int kt = (tile / 12) * 64, nt = (tile % 12) * 64;
        const float* src = Wm + (size_t)mi * HH;
        u16* dst = WtAll + (size_t)mi * HH;
        float(*tl)[65] = (float(*)[65])sh;
        int r = t >> 2, cq = (t & 3) * 16;
        int row = kt + r;
#pragma unroll
        for (int q = 0; q < 4; q++) {
            float4 v = *(const float4*)(src + (size_t)row * kH + nt + cq + q * 4);
            tl[r][cq + q * 4 + 0] = v.x;
            tl[r][cq + q * 4 + 1] = v.y;
            tl[r][cq + q * 4 + 2] = v.z;
            tl[r][cq + q * 4 + 3] = v.w;
        }
        __syncthreads();
        u16* drow = dst + (size_t)(nt + r) * kH + kt + cq;
#pragma unroll
        for (int j = 0; j < 16; j++) drow[j] = f2bf(tl[cq + j][r]);
    } else if (bx < 2656) {
        int gx = bx - 1888;
        int p = gx / 192;
        int wid = t >> 6, lane = t & 63;
        int row = (gx % 192) * 4 + wid;
        const int wmI[4] = {0, 1, 8, 9};
        const float* W  = Wm + (size_t)wmI[p] * HH + (size_t)row * kH;
        const float* wa = fc_w + (size_t)((p & 1) ? 6 : 4) * kH;
        const float* wb = wa + kH;
        float sa = 0.f, sb = 0.f;
        for (int c = lane; c < kH; c += 64) {
            float wv = W[c];
            sa += wv * wa[c];
            sb += wv * wb[c];
        }
#pragma unroll
        for (int off = 32; off; off >>= 1) {
            sa += __shfl_xor(sa, off, 64);
            sb += __shfl_xor(sb, off, 64);
        }
        if (lane == 0) {
            if (p < 2) {
                uA[(2 * p) * kH + row]     = sa;
                uA[(2 * p + 1) * kH + row] = sb;
            } else {
                int q = p - 2;
                uB[(2 * q) * kH + row]     = sa + wa[row];
                uB[(2 * q + 1) * kH + row] = sb + wb[row];
            }
        }
    } else if (bx < 2720) {
        int r = bx - 2656;
        for (int h = t; h < kH; h += 256) relembB[r * kH + h] = f2bf(rel_embs[r * kH + h]);
    } else if (bx < 2724) {
        int r = bx - 2720;
        for (int h = t; h < kH; h += 256) hgsB[r * kH + h] = f2bf(h_gs[r * kH + h]);
    } else if (bx < 2788) {
        int r = bx - 2724;
        if (t < kTE) sh[t] = rel_transe[r * kTE + t];
        __syncthreads();
        float a0 = rproj_b[t], a1 = rproj_b[t + 256], a2 = rproj_b[t + 512];
        for (int k = 0; k < kTE; k++) {
            float rv = sh[k];
            const float* wr = rproj_w + (size_t)k * kH;
            a0 = fmaf(rv, wr[t], a0);
            a1 = fmaf(rv, wr[t + 256], a1);
            a2 = fmaf(rv, wr[t + 512], a2);
        }
        brelB[r * kH + t]       = f2bf(a0);
        brelB[r * kH + t + 256] = f2bf(a1);
        brelB[r * kH + t + 512] = f2bf(a2);
    } else {
        int j = bx - 2788;
        const int wbI[8] = {0, 0, 1, 1, 8, 8, 9, 9};
        const int fcI[8] = {4, 5, 6, 7, 4, 5, 6, 7};
        const float* wb = Wb + (size_t)wbI[j] * kH;
        const float* w  = fc_w + (size_t)fcI[j] * kH;
        float s = 0.f;
        for (int h = t; h < kH; h += 256) s += wb[h] * w[h];
#pragma unroll
        for (int off = 32; off; off >>= 1) s += __shfl_down(s, off, 64);
        int wid = t >> 6;
        if ((t & 63) == 0) sh[wid] = s;
        __syncthreads();
        if (t == 0) cc[j] = sh[0] + sh[1] + sh[2] + sh[3];
    }
}

// ---- 2. per-token uA/uB dots (coalesced) + batched MFMA GEMM ----
struct GemmJob {
    const u16* A; const u16* Wt; const float* bias;
    float* C; u16* Cbf; const float* rowmask;
    int M; int K; int ldc; int coff;
};
struct GemmBatch { GemmJob j[6]; };

__device__ inline int swz(int row, int slot) {   // short-index into [row][64] layout
    return row * 64 + ((slot ^ (row & 7)) << 3);
}

__global__ __launch_bounds__(256) void k_dots_gemm(GemmBatch batch,
        const float* __restrict__ embs,
        const float* __restrict__ uA, const float* __restrict__ uB,
        float* __restrict__ dA, float* __restrict__ dB)
{
    __shared__ short Als[2][64 * 64];      // 16 KB
    __shared__ short Bls[2][64 * 64];      // 16 KB
    int bx = blockIdx.x;
    if (bx < 1024) {
        int tok = bx, t = threadIdx.x;
        const float* e = embs + (size_t)tok * kH;
        float s[8] = {0, 0, 0, 0, 0, 0, 0, 0};
        for (int h = t; h < kH; h += 256) {
            float x = e[h];
#pragma unroll
            for (int j = 0; j < 4; j++) {
                s[j]     += x * uA[j * kH + h];
                s[4 + j] += x * uB[j * kH + h];
            }
        }
#pragma unroll
        for (int off = 32; off; off >>= 1)
#pragma unroll
            for (int j = 0; j < 8; j++) s[j] += __shfl_down(s[j], off, 64);
        float(*red)[4] = (float(*)[4])&Als[0][0];
        int wid = t >> 6;
        if ((t & 63) == 0) {
#pragma unroll
            for (int j = 0; j < 8; j++) red[j][wid] = s[j];
        }
        __syncthreads();
        if (t == 0) {
#pragma unroll
            for (int j = 0; j < 4; j++) {
                dA[j * 1024 + tok] = red[j][0] + red[j][1] + red[j][2] + red[j][3];
                dB[j * 1024 + tok] = red[4 + j][0] + red[4 + j][1] + red[4 + j][2] + red[4 + j][3];
            }
        }
        return;
    }
    // ---- GEMM tile: flat index -> (job, m-tile, n-tile) ----
    int g = bx - 1024;
    int jz, mx, ny;
    if (g < 48)       { jz = g / 12;            mx = 0;              ny = g % 12; }
    else if (g < 240) { jz = 4;                 mx = (g - 48) / 12;  ny = (g - 48) % 12; }
    else              { jz = 5;                 mx = (g - 240) / 12; ny = (g - 240) % 12; }
    GemmJob jb = batch.j[jz];

    int tid = threadIdx.x;
    int m0 = mx * 64;
    int n0 = ny * 64;
    int w = tid >> 6, lane = tid & 63;
    int wm = (w >> 1) * 32, wn = (w & 1) * 32;   // 2M x 2N waves, each 32x32
    int lrow = lane & 15, lhi = lane >> 4;
    int srow = tid >> 2, sc0 = tid & 3;          // chunks sc0 and sc0+4
    int K = jb.K;
    int T = K >> 6;

    f32x4 zero4 = {0.f, 0.f, 0.f, 0.f};
    f32x4 acc[2][2];
#pragma unroll
    for (int i = 0; i < 2; i++)
#pragma unroll
        for (int j = 0; j < 2; j++) acc[i][j] = zero4;

    bf16x8 pa[2], pb[2];

#define LOADT(k0)                                                                 \
    {                                                                             \
        _Pragma("unroll")                                                         \
        for (int q = 0; q < 2; q++) {                                             \
            bf16x8 va;                                                            \
            _Pragma("unroll") for (int z = 0; z < 8; z++) va[z] = 0;              \
            if (m0 + srow < jb.M)                                                 \
                va = *reinterpret_cast<const bf16x8*>(                            \
                    jb.A + (size_t)(m0 + srow) * K + (k0) + (sc0 + q * 4) * 8);   \
            pa[q] = va;                                                           \
            pb[q] = *reinterpret_cast<const bf16x8*>(                             \
                jb.Wt + (size_t)(n0 + srow) * K + (k0) + (sc0 + q * 4) * 8);      \
        }                                                                         \
    }
#define STORET(buf)                                                               \
    {                                                                             \
        _Pragma("unroll")                                                         \
        for (int q = 0; q < 2; q++) {                                             \
            *reinterpret_cast<bf16x8*>(&Als[buf][swz(srow, sc0 + q * 4)]) = pa[q];\
            *reinterpret_cast<bf16x8*>(&Bls[buf][swz(srow, sc0 + q * 4)]) = pb[q];\
        }                                                                         \
    }

    LOADT(0);
    STORET(0);
    __syncthreads();
    int cur = 0;
    for (int t = 0; t < T; t++) {
        if (t + 1 < T) LOADT((t + 1) << 6);
#pragma unroll
        for (int sub = 0; sub < 2; sub++) {
            bf16x8 af[2], bg[2];
#pragma unroll
            for (int i = 0; i < 2; i++) {
                af[i] = *reinterpret_cast<const bf16x8*>(
                    &Als[cur][swz(wm + i * 16 + lrow, sub * 4 + lhi)]);
                bg[i] = *reinterpret_cast<const bf16x8*>(
                    &Bls[cur][swz(wn + i * 16 + lrow, sub * 4 + lhi)]);
            }
#pragma unroll
            for (int i = 0; i < 2; i++)
#pragma unroll
                for (int j = 0; j < 2; j++)
                    acc[i][j] = __builtin_amdgcn_mfma_f32_16x16x32_bf16(af[i], bg[j], acc[i][j], 0, 0, 0);
        }
        if (t + 1 < T) STORET(cur ^ 1);
        __syncthreads();
        cur ^= 1;
    }
#undef LOADT
#undef STORET

#pragma unroll
    for (int i = 0; i < 2; i++) {
#pragma unroll
        for (int j = 0; j < 2; j++) {
            int n = n0 + wn + j * 16 + lrow;
            float bi = jb.bias[n];
#pragma unroll
            for (int q = 0; q < 4; q++) {
                int m = m0 + wm + i * 16 + lhi * 4 + q;
                if (m < jb.M) {
                    float val = acc[i][j][q] + bi;
                    if (jb.rowmask) val = (jb.rowmask[m] != 0.f) ? val : 0.f;
                    if (jb.C)   jb.C[(size_t)m * jb.ldc + jb.coff + n] = val;
                    if (jb.Cbf) jb.Cbf[(size_t)m * jb.ldc + jb.coff + n] = f2bf(val);
                }
            }
        }
    }
}

// ---- 3. attention: scores (4-row ILP, trans tanh) + softmax + c-dots; r==0 scan->t ----
__global__ __launch_bounds__(512) void k_score(const u16* __restrict__ tokpB,
        const float* __restrict__ relpf, const float* __restrict__ relpb,
        const float* __restrict__ hgpf, const float* __restrict__ hgpb,
        const float* __restrict__ V_w, const float* __restrict__ V_b,
        const float* __restrict__ dd, const float* __restrict__ dA,
        const float* __restrict__ dB, const float* __restrict__ cc,
        const float* __restrict__ logits,
        float* __restrict__ c4, float* __restrict__ c5,
        float* __restrict__ c6, float* __restrict__ c7,
        float* __restrict__ t4, float* __restrict__ t5,
        float* __restrict__ t6, float* __restrict__ t7)
{
    constexpr float C = 2.8853900817779268f;   // 2*log2(e)
    int idx = blockIdx.x;            // 512
    int which = idx >> 8, b = (idx >> 6) & 3, r = idx & 63;
    int tid = threadIdx.x;
    int wid = tid >> 6, lane = tid & 63;
    int h0 = lane * 12;
    const float* relp = (which ? relpb : relpf) + (size_t)r * kH + h0;
    const float* hgp  = (which ? hgpb : hgpf) + (size_t)b * kH + h0;
    const float* vw   = V_w + h0;

    __shared__ float sc[kL];
    __shared__ float red2[2][8];
    __shared__ float PA0[kL], PA1[kL], pv0[kL], pv1[kL];
    __shared__ int warr[4];
    __shared__ int itot[4];
    __shared__ float ftot0[4], ftot1[4];

    float av2[12], w2[12], wsum = 0.f;
#pragma unroll
    for (int j = 0; j < 12; j++) {
        av2[j] = C * (relp[j] + hgp[j]);
        float wv = vw[j];
        w2[j] = -2.f * wv;
        wsum += wv;
    }
    float vb = V_b[0];
    const u16* base = tokpB + ((size_t)which * (kB * kL) + b * kL) * kH + h0;

    int l0 = wid * 32;
    // 4 rows per iteration: 4 independent acc chains, 48 independent trans
    // ops in flight per wave iteration -> hides trans/VALU latency.
    for (int l = l0; l < l0 + 32; l += 4) {
        bf16x4 x[4][3];
#pragma unroll
        for (int q = 0; q < 4; q++) {
            const u16* row = base + (size_t)(l + q) * kH;
            x[q][0] = *reinterpret_cast<const bf16x4*>(row);
            x[q][1] = *reinterpret_cast<const bf16x4*>(row + 4);
            x[q][2] = *reinterpret_cast<const bf16x4*>(row + 8);
        }
        float acc[4] = {wsum, wsum, wsum, wsum};
#pragma unroll
        for (int c3 = 0; c3 < 3; c3++) {
#pragma unroll
            for (int j = 0; j < 4; j++) {
                int hj = c3 * 4 + j;
                float e0 = fast_exp2(fmaf(bf2f((u16)x[0][c3][j]), C, av2[hj]));
                float e1 = fast_exp2(fmaf(bf2f((u16)x[1][c3][j]), C, av2[hj]));
                float e2 = fast_exp2(fmaf(bf2f((u16)x[2][c3][j]), C, av2[hj]));
                float e3 = fast_exp2(fmaf(bf2f((u16)x[3][c3][j]), C, av2[hj]));
                acc[0] = fmaf(w2[hj], fast_rcp(e0 + 1.f), acc[0]);
                acc[1] = fmaf(w2[hj], fast_rcp(e1 + 1.f), acc[1]);
                acc[2] = fmaf(w2[hj], fast_rcp(e2 + 1.f), acc[2]);
                acc[3] = fmaf(w2[hj], fast_rcp(e3 + 1.f), acc[3]);
            }
        }
#pragma unroll
        for (int off = 32; off; off >>= 1) {
#pragma unroll
            for (int q = 0; q < 4; q++) acc[q] += __shfl_xor(acc[q], off, 64);
        }
        if (lane == 0) {
#pragma unroll
            for (int q = 0; q < 4; q++) sc[l + q] = acc[q] + vb;
        }
    }
    __syncthreads();

    // softmax over sc[0..255] + c-dots (A never materialized)
    int l = tid & 255;
    bool act = tid < 256;
    float x = act ? sc[l] : -3.4e38f;
    float m = x;
#pragma unroll
    for (int off = 32; off; off >>= 1) m = fmaxf(m, __shfl_xor(m, off, 64));
    if (lane == 0) red2[0][wid] = m;
    __syncthreads();
    m = fmaxf(fmaxf(red2[0][0], red2[0][1]), fmaxf(red2[0][2], red2[0][3]));
    float p = act ? __expf(x - m) : 0.f;
    float s = p;
#pragma unroll
    for (int off = 32; off; off >>= 1) s += __shfl_xor(s, off, 64);
    __syncthreads();
    if (lane == 0) red2[0][wid] = s;
    __syncthreads();
    s = red2[0][0] + red2[0][1] + red2[0][2] + red2[0][3];
    float a = p / s;
    const float* ddA = dd + (size_t)(which ? 2 : 0) * 1024 + b * 256;
    const float* ddB = dd + (size_t)(which ? 3 : 1) * 1024 + b * 256;
    float q0 = act ? a * ddA[l] : 0.f;
    float q1 = act ? a * ddB[l] : 0.f;
#pragma unroll
    for (int off = 32; off; off >>= 1) {
        q0 += __shfl_xor(q0, off, 64);
        q1 += __shfl_xor(q1, off, 64);
    }
    __syncthreads();
    if (lane == 0) { red2[0][wid] = q0; red2[1][wid] = q1; }
    __syncthreads();
    if (tid == 0) {
        float cv0 = red2[0][0] + red2[0][1] + red2[0][2] + red2[0][3];
        float cv1 = red2[1][0] + red2[1][1] + red2[1][2] + red2[1][3];
        int loc = b * kR + r;
        if (which) { c6[loc] = cv0; c7[loc] = cv1; }
        else       { c4[loc] = cv0; c5[loc] = cv1; }
    }

    if (r != 0) return;
    // ---- r==0 blocks only: shuffle-scan -> t vectors (coalesced writes) ----
    int p0 = which ? 2 : 0, p1 = p0 + 1;
    const float* slog = logits + (which ? OFF_BOS : OFF_FSS) + (size_t)b * kL;
    const float* elog = logits + (which ? OFF_BOE : OFF_FSE) + (size_t)b * kL;
    bool st = false;
    int smv = kL;
    float a0v = 0.f, a1v = 0.f;
    if (act) {
        st = slog[l] > 0.f;                       // sigmoid(x)>0.5 <=> x>0
        smv = (elog[l] > 0.f) ? l : kL;
        a0v = dA[(size_t)p0 * 1024 + b * 256 + l];
        a1v = dA[(size_t)p1 * 1024 + b * 256 + l];
    }
    int sv = smv;
#pragma unroll
    for (int off2 = 1; off2 < 64; off2 <<= 1) {
        int o = __shfl_down(sv, off2, 64);
        if (lane + off2 < 64) sv = min(sv, o);
    }
    if (act && lane == 0) warr[wid] = sv;
    __syncthreads();
    int next_end = sv;
    if (act)
        for (int w2 = wid + 1; w2 < 4; w2++) next_end = min(next_end, warr[w2]);
    int validi = (act && st && next_end < kL) ? 1 : 0;
    int px = validi;
    float q0v = a0v, q1v = a1v;
#pragma unroll
    for (int off2 = 1; off2 < 64; off2 <<= 1) {
        int oi = __shfl_up(px, off2, 64);
        float o0 = __shfl_up(q0v, off2, 64);
        float o1 = __shfl_up(q1v, off2, 64);
        if (lane >= off2) { px += oi; q0v += o0; q1v += o1; }
    }
    if (act && lane == 63) { itot[wid] = px; ftot0[wid] = q0v; ftot1[wid] = q1v; }
    __syncthreads();
    if (act) {
        for (int w2 = 0; w2 < wid; w2++) { px += itot[w2]; q0v += ftot0[w2]; q1v += ftot1[w2]; }
        PA0[l] = q0v; PA1[l] = q1v;
        pv0[l] = 0.f; pv1[l] = 0.f;
    }
    __syncthreads();
    if (validi) {
        int j = next_end;
        int rk = px - 1;
        float inv = 1.f / (float)(j - l + 1);
        float lo0 = l ? PA0[l - 1] : 0.f;
        float lo1 = l ? PA1[l - 1] : 0.f;
        pv0[rk] = (PA0[j] - lo0) * inv;
        pv1[rk] = (PA1[j] - lo1) * inv;
    }
    __syncthreads();
    if (act) {
        int num = itot[0] + itot[1] + itot[2] + itot[3];
        float tv0 = ((l < num) ? (pv0[l] + cc[p0]) : 0.f)
                  + dB[(size_t)p0 * 1024 + b * 256 + l] + cc[4 + p0];
        float tv1 = ((l < num) ? (pv1[l] + cc[p1]) : 0.f)
                  + dB[(size_t)p1 * 1024 + b * 256 + l] + cc[4 + p1];
        if (which) { t6[b * kL + l] = tv0; t7[b * kL + l] = tv1; }
        else       { t4[b * kL + l] = tv0; t5[b * kL + l] = tv1; }
    }
}

// ---- 4. final broadcast-add (fully coalesced) ----
__global__ __launch_bounds__(64) void k_final(const float* __restrict__ t4,
        const float* __restrict__ t5, const float* __restrict__ t6,
        const float* __restrict__ t7, const float* __restrict__ c4,
        const float* __restrict__ c5, const float* __restrict__ c6,
        const float* __restrict__ c7, const float* __restrict__ fc_b,
        float* __restrict__ out)
{
    int which = blockIdx.x >> 10;
    int t = blockIdx.x & 1023;
    int b = t >> 8;
    int r = threadIdx.x;
    if (!which) {
        out[OFF_FOS + (size_t)t * kR + r] = t4[t] + c4[b * kR + r] + fc_b[4];
        out[OFF_FOE + (size_t)t * kR + r] = t5[t] + c5[b * kR + r] + fc_b[5];
    } else {
        out[OFF_BSS + (size_t)t * kR + r] = t6[t] + c6[b * kR + r] + fc_b[6];
        out[OFF_BSE + (size_t)t * kR + r] = t7[t] + c7[b * kR + r] + fc_b[7];
    }
}

extern "C" void kernel_launch(void* const* d_in, const int* in_sizes, int n_in,
                              void* d_out, int out_size, void* d_ws, size_t ws_size,
                              hipStream_t stream)
{
    const float* embs       = (const float*)d_in[0];
    const float* h_gs       = (const float*)d_in[1];
    const float* rel_embs   = (const float*)d_in[2];
    const float* rel_transe = (const float*)d_in[3];
    const float* fc_w       = (const float*)d_in[4];
    const float* fc_b       = (const float*)d_in[5];
    const float* Wm         = (const float*)d_in[6];
    const float* Wb         = (const float*)d_in[7];
    const float* V_w        = (const float*)d_in[8];
    const float* V_b        = (const float*)d_in[9];
    const float* rproj_w    = (const float*)d_in[10];
    const float* rproj_b    = (const float*)d_in[11];
    float* out = (float*)d_out;
    float* ws  = (float*)d_ws;

    u16* WtAll   = (u16*)(ws + WS_WTALL);
    u16* embsB   = (u16*)(ws + WS_EMBSB);
    u16* relembB = (u16*)(ws + WS_RELEMBB);
    u16* hgsB    = (u16*)(ws + WS_HGSB);
    u16* brelB   = (u16*)(ws + WS_BRELB);
    u16* tokpB   = (u16*)(ws + WS_TOKPB);
    float* relpf = ws + WS_RELPF;
    float* relpb = ws + WS_RELPB;
    float* hgpf  = ws + WS_HGPF;
    float* hgpb  = ws + WS_HGPB;
    float* dd    = ws + WS_DD;
    float* dA    = ws + WS_DA;
    float* dB    = ws + WS_DB;
    float* uA    = ws + WS_UA;
    float* uB    = ws + WS_UB;
    float* cc    = ws + WS_CC;
    float* c4 = ws + WS_C4; float* c5 = ws + WS_C5;
    float* c6 = ws + WS_C6; float* c7 = ws + WS_C7;
    float* t4 = ws + WS_T4; float* t5 = ws + WS_T5;
    float* t6 = ws + WS_T6; float* t7 = ws + WS_T7;

    // 1. mega-prep (everything depending only on inputs)
    k_prep_all<<<2796, 256, 0, stream>>>(embs, rel_embs, h_gs, rel_transe,
        fc_w, fc_b, Wm, Wb, rproj_w, rproj_b,
        out, embsB, relembB, hgsB, brelB, WtAll, uA, uB, cc, dd);

    // 2. per-token uA/uB dots (coalesced) + gemmA
    {
        GemmBatch bt;
        bt.j[0] = { relembB, WtAll + 2 * HH, Wb + 2 * kH, relpf, nullptr, nullptr, kR, kH, kH, 0 };
        bt.j[1] = { hgsB,    WtAll + 3 * HH, Wb + 3 * kH, hgpf,  nullptr, nullptr, kB, kH, kH, 0 };
        bt.j[2] = { hgsB,    WtAll + 6 * HH, Wb + 6 * kH, hgpb,  nullptr, nullptr, kB, kH, kH, 0 };
        bt.j[3] = { brelB,   WtAll + 5 * HH, Wb + 5 * kH, relpb, nullptr, nullptr, kR, kH, kH, 0 };
        bt.j[4] = { embsB,   WtAll + 4 * HH, Wb + 4 * kH, nullptr, tokpB,            nullptr, kB * kL, kH, kH, 0 };
        bt.j[5] = { embsB,   WtAll + 7 * HH, Wb + 7 * kH, nullptr, tokpB + (size_t)kB * kL * kH, nullptr, kB * kL, kH, kH, 0 };
        k_dots_gemm<<<1456, 256, 0, stream>>>(bt, embs, uA, uB, dA, dB);
    }

    // 3. fused scores + softmax + c-dots (+ scan/t on r==0 blocks)
    k_score<<<512, 512, 0, stream>>>(tokpB, relpf, relpb, hgpf, hgpb, V_w, V_b,
                                     dd, dA, dB, cc, out,
                                     c4, c5, c6, c7, t4, t5, t6, t7);

    // 4. final coalesced broadcast-add
    k_final<<<2 * kB * kL, 64, 0, stream>>>(t4, t5, t6, t7, c4, c5, c6, c7, fc_b, out);
}